// Round 1
// baseline (216.347 us; speedup 1.0000x reference)
//
#include <hip/hip_runtime.h>

#define B_ 16
#define D_ 64
#define T_ 4096
#define K_ 512
#define N_ (B_*T_)        // 65536 vectors
#define Q_ (B_*D_*T_)     // 4194304 quantized elements
#define ENC_OFF ((size_t)(2 + Q_))  // encodings start in d_out

// ws layout (bytes) — ~400 KB
#define WS_NE    0          // float[512]
#define WS_LPART 2048       // float[1024]  per-block loss partials
#define WS_GIDX  6144       // int[65536]   per-row argmin index (256 KB)
#define WS_CBH   268288     // bf16x8[32*2*64] (64 KB) codebook hi frags
#define WS_CBL   333824     // bf16x8[32*2*64] (64 KB) codebook lo frags

typedef __bf16 bf16x8 __attribute__((ext_vector_type(8)));
typedef float  f32x4  __attribute__((ext_vector_type(4)));

// ---------------- K0: ne + codebook hi/lo B-fragments ----------------------
// Grid = 16 blocks x 256 threads (widened from 8 to cut latency-bound tail).
__global__ __launch_bounds__(256) void k0_init(const float* __restrict__ cb,
                                               float* __restrict__ ne,
                                               bf16x8* __restrict__ cbh,
                                               bf16x8* __restrict__ cbl) {
    int bidx = blockIdx.x, tid = threadIdx.x;

    // ne: 32 codes per block, 8 lanes per code
    {
        int code = bidx * 32 + (tid >> 3), sl = tid & 7;
        float s = 0.f;
#pragma unroll
        for (int j = 0; j < 8; ++j) { float c = cb[code * 64 + sl * 8 + j]; s = fmaf(c, c, s); }
        s += __shfl_xor(s, 1); s += __shfl_xor(s, 2); s += __shfl_xor(s, 4);
        if (sl == 0) ne[code] = s;
    }

    // B-frag element (ct,ks,lane,j) = cb[ct*16 + (lane&15)][ks*32 + (lane>>4)*8 + j]
    // 4096 entries over 16 blocks -> 1 per thread
    int e = bidx * 256 + tid;
    int ct = e >> 7, ks = (e >> 6) & 1, lane = e & 63;
    int code  = ct * 16 + (lane & 15);
    int dbase = ks * 32 + ((lane >> 4) << 3);
    bf16x8 h, l;
#pragma unroll
    for (int j = 0; j < 8; ++j) {
        float v = cb[code * 64 + dbase + j];
        __bf16 hv = (__bf16)v;
        __bf16 lv = (__bf16)(v - (float)hv);
        h[j] = hv; l[j] = lv;
    }
    cbh[(ct * 2 + ks) * 64 + lane] = h;
    cbl[(ct * 2 + ks) * 64 + lane] = l;
}

// ---------------- K_MAIN: stage + MFMA argmin + one-hot + quant + loss ------
// Block = 256 thr = 4 waves = 64 rows (4 row-tiles, 1 per wave); grid = 1024.
// NO device-scope atomics: per-row idx -> gidx, per-block loss -> lpart.
__global__ __launch_bounds__(256) void k_main(const float* __restrict__ in,
                                              const float* __restrict__ cb,
                                              const bf16x8* __restrict__ cbh,
                                              const bf16x8* __restrict__ cbl,
                                              const float* __restrict__ ne,
                                              float* __restrict__ out,
                                              float2* __restrict__ enc2,
                                              int* __restrict__ gidx,
                                              float* __restrict__ lpart) {
    __shared__ float X[64][65];      // 16.6 KB; all access patterns <=2-way alias (free)
    __shared__ float ne_s[512];
    __shared__ int   sidx[64];
    int tid = threadIdx.x;
    int n0 = blockIdx.x * 64;
    int b  = n0 >> 12, t0 = n0 & (T_ - 1);

    { // stage x-tile: 4096 floats, 16 per thread, coalesced
        int tl = tid & 63, dg = tid >> 6;
#pragma unroll
        for (int i = 0; i < 16; ++i) {
            int d = dg * 16 + i;
            X[d][tl] = in[((size_t)b * 64 + d) * T_ + t0 + tl];
        }
    }
    ne_s[tid] = ne[tid];
    ne_s[tid + 256] = ne[tid + 256];
    __syncthreads();

    int w = tid >> 6, lane = tid & 63;
    int col = lane & 15, q = lane >> 4;

    // A-frags: wave w owns row-tile w. A[m][k=ks*32+q*8+j] = x_row[d]
    bf16x8 Ah[2], Al[2];
#pragma unroll
    for (int ks = 0; ks < 2; ++ks) {
        bf16x8 h, l;
#pragma unroll
        for (int j = 0; j < 8; ++j) {
            float v = X[ks * 32 + q * 8 + j][w * 16 + col];
            __bf16 hv = (__bf16)v;
            __bf16 lv = (__bf16)(v - (float)hv);
            h[j] = hv; l[j] = lv;
        }
        Ah[ks] = h; Al[ks] = l;
    }

    float m1[4]; int i1[4];
#pragma unroll
    for (int e = 0; e < 4; ++e) { m1[e] = 3.4e38f; i1[e] = 0; }

    for (int ct = 0; ct < 32; ++ct) {
        bf16x8 Bh0 = cbh[(ct * 2 + 0) * 64 + lane];
        bf16x8 Bh1 = cbh[(ct * 2 + 1) * 64 + lane];
        bf16x8 Bl0 = cbl[(ct * 2 + 0) * 64 + lane];
        bf16x8 Bl1 = cbl[(ct * 2 + 1) * 64 + lane];
        float nev = ne_s[ct * 16 + col];
        int code = ct * 16 + col;
        f32x4 acc = {0.f, 0.f, 0.f, 0.f};
        acc = __builtin_amdgcn_mfma_f32_16x16x32_bf16(Ah[0], Bh0, acc, 0, 0, 0);
        acc = __builtin_amdgcn_mfma_f32_16x16x32_bf16(Ah[1], Bh1, acc, 0, 0, 0);
        acc = __builtin_amdgcn_mfma_f32_16x16x32_bf16(Ah[0], Bl0, acc, 0, 0, 0);
        acc = __builtin_amdgcn_mfma_f32_16x16x32_bf16(Al[0], Bh0, acc, 0, 0, 0);
        acc = __builtin_amdgcn_mfma_f32_16x16x32_bf16(Ah[1], Bl1, acc, 0, 0, 0);
        acc = __builtin_amdgcn_mfma_f32_16x16x32_bf16(Al[1], Bh1, acc, 0, 0, 0);
        // lo*lo terms ~2^-32 relative: negligible, dropped
#pragma unroll
        for (int e = 0; e < 4; ++e) {
            float sc = fmaf(-2.f, acc[e], nev);   // ||e||^2 - 2 x.e
            bool lt = sc < m1[e];
            i1[e] = lt ? code : i1[e];
            m1[e] = lt ? sc : m1[e];
        }
    }

    // argmin across the 16 lanes (same q) holding this row's columns
#pragma unroll
    for (int e = 0; e < 4; ++e) {
        float a1 = m1[e]; int ai = i1[e];
#pragma unroll
        for (int off = 1; off < 16; off <<= 1) {
            float o1 = __shfl_xor(a1, off);
            int   oi = __shfl_xor(ai, off);
            bool tk = (o1 < a1) || (o1 == a1 && oi < ai);  // tie -> lower index
            a1 = tk ? o1 : a1; ai = tk ? oi : ai;
        }
        if (col == 0) sidx[w * 16 + q * 4 + e] = ai;
    }
    __syncthreads();

    // --- one-hot rows: 256 float2 cols per row, 64 rows (base 8B-aligned) ---
#pragma unroll 4
    for (int i = 0; i < 64; ++i) {
        int id = sidx[i];                      // uniform LDS read -> broadcast
        float2 v;
        v.x = ((id >> 1) == tid && (id & 1) == 0) ? 1.f : 0.f;
        v.y = ((id >> 1) == tid && (id & 1) == 1) ? 1.f : 0.f;
        enc2[(size_t)(n0 + i) * 256 + tid] = v;
    }

    // --- quantized + loss: lane = row, 16 dims per thread ---
    int tl = tid & 63, dg = tid >> 6;
    int idq = sidx[tl];
    const float4* cq4 = (const float4*)(cb + (size_t)idq * 64 + dg * 16);
    float* qp = out + 1 + (size_t)b * D_ * T_ + (size_t)(dg * 16) * T_ + t0 + tl;

    float lsum = 0.f;
#pragma unroll
    for (int j4 = 0; j4 < 4; ++j4) {
        float4 qv = cq4[j4];
        float qe[4] = {qv.x, qv.y, qv.z, qv.w};
#pragma unroll
        for (int e = 0; e < 4; ++e) {
            int dl = j4 * 4 + e;               // 0..15
            float xv = X[dg * 16 + dl][tl];
            float diff = qe[e] - xv;
            lsum = fmaf(diff, diff, lsum);
            qp[(size_t)dl * T_] = xv + diff;   // straight-through: x + (q - x)
        }
    }
    if (tid < 64) gidx[n0 + tid] = idq;        // coalesced plain store, no atomic

#pragma unroll
    for (int off = 32; off > 0; off >>= 1) lsum += __shfl_down(lsum, off);
    __shared__ float wsum[4];
    if ((tid & 63) == 0) wsum[tid >> 6] = lsum;
    __syncthreads();
    if (tid == 0)
        lpart[blockIdx.x] = wsum[0] + wsum[1] + wsum[2] + wsum[3];
}

// ---------------- K6: hist from gidx (LDS) + loss reduce + perplexity -------
__global__ __launch_bounds__(512) void k6_final(const int* __restrict__ gidx,
                                                const float* __restrict__ lpart,
                                                float* __restrict__ out) {
    __shared__ int    h[512];
    __shared__ double sh[512];
    __shared__ double sl2[512];
    int k = threadIdx.x;
    h[k] = 0;
    __syncthreads();
#pragma unroll 4
    for (int i = 0; i < 128; ++i)
        atomicAdd(&h[gidx[(size_t)i * 512 + k]], 1);   // LDS atomics only
    double ls = (double)lpart[k] + (double)lpart[k + 512];
    __syncthreads();
    double p = (double)h[k] / (double)N_;
    sh[k]  = p * log(p + 1e-10);
    sl2[k] = ls;
    __syncthreads();
    for (int s = 256; s > 0; s >>= 1) {
        if (k < s) { sh[k] += sh[k + s]; sl2[k] += sl2[k + s]; }
        __syncthreads();
    }
    if (k == 0) {
        out[1 + Q_] = (float)exp(-sh[0]);
        out[0] = (float)(1.25 * sl2[0] / (double)Q_);
    }
}

extern "C" void kernel_launch(void* const* d_in, const int* in_sizes, int n_in,
                              void* d_out, int out_size, void* d_ws, size_t ws_size,
                              hipStream_t stream) {
    const float* in = (const float*)d_in[0];   // [16, 64, 4096] fp32
    const float* cb = (const float*)d_in[1];   // [512, 64] fp32
    float* out = (float*)d_out;
    char* ws = (char*)d_ws;

    float* ne     = (float*)(ws + WS_NE);
    float* lpart  = (float*)(ws + WS_LPART);
    int*   gidx   = (int*)(ws + WS_GIDX);
    bf16x8* cbh   = (bf16x8*)(ws + WS_CBH);
    bf16x8* cbl   = (bf16x8*)(ws + WS_CBL);

    float2* enc2 = (float2*)(out + ENC_OFF);

    k0_init<<<16, 256, 0, stream>>>(cb, ne, cbh, cbl);
    k_main<<<N_ / 64, 256, 0, stream>>>(in, cb, cbh, cbl, ne, out, enc2, gidx, lpart);
    k6_final<<<1, 512, 0, stream>>>(gidx, lpart, out);
}

// Round 2
// 203.852 us; speedup vs baseline: 1.0613x; 1.0613x over previous
//
#include <hip/hip_runtime.h>

#define B_ 16
#define D_ 64
#define T_ 4096
#define K_ 512
#define N_ (B_*T_)        // 65536 vectors
#define Q_ (B_*D_*T_)     // 4194304 quantized elements
#define ENC_OFF ((size_t)(2 + Q_))  // encodings start in d_out

// ws layout (bytes) — ~136 KB  (reverted to R0 layout: hist/loss atomics were cheap)
#define WS_LOSS    0        // double
#define WS_HIST    16       // int[512]
#define WS_NE      2064     // float[512]
#define WS_CBH     4608     // bf16x8[32*2*64]  (64 KB) codebook hi frags
#define WS_CBL     70144    // bf16x8[32*2*64]  (64 KB) codebook lo frags

typedef __bf16 bf16x8 __attribute__((ext_vector_type(8)));
typedef float  f32x4  __attribute__((ext_vector_type(4)));

// ---------------- K0: init + ne + codebook hi/lo B-fragments ----------------
// Grid = 16 blocks x 256 threads.
__global__ __launch_bounds__(256) void k0_init(const float* __restrict__ cb,
                                               float* __restrict__ ne,
                                               int* __restrict__ hist,
                                               double* __restrict__ loss,
                                               bf16x8* __restrict__ cbh,
                                               bf16x8* __restrict__ cbl) {
    int bidx = blockIdx.x, tid = threadIdx.x;

    // ne: 32 codes per block, 8 lanes per code
    {
        int code = bidx * 32 + (tid >> 3), sl = tid & 7;
        float s = 0.f;
#pragma unroll
        for (int j = 0; j < 8; ++j) { float c = cb[code * 64 + sl * 8 + j]; s = fmaf(c, c, s); }
        s += __shfl_xor(s, 1); s += __shfl_xor(s, 2); s += __shfl_xor(s, 4);
        if (sl == 0) ne[code] = s;
    }
    if (bidx == 0) {
        hist[tid] = 0; hist[tid + 256] = 0;
        if (tid == 0) *loss = 0.0;
    }

    // B-frag element (ct,ks,lane,j) = cb[ct*16 + (lane&15)][ks*32 + (lane>>4)*8 + j]
    // 4096 entries over 16 blocks -> 1 per thread
    int e = bidx * 256 + tid;
    int ct = e >> 7, ks = (e >> 6) & 1, lane = e & 63;
    int code  = ct * 16 + (lane & 15);
    int dbase = ks * 32 + ((lane >> 4) << 3);
    bf16x8 h, l;
#pragma unroll
    for (int j = 0; j < 8; ++j) {
        float v = cb[code * 64 + dbase + j];
        __bf16 hv = (__bf16)v;
        __bf16 lv = (__bf16)(v - (float)hv);
        h[j] = hv; l[j] = lv;
    }
    cbh[(ct * 2 + ks) * 64 + lane] = h;
    cbl[(ct * 2 + ks) * 64 + lane] = l;
}

// ---------------- K_MAIN: stage + MFMA argmin + one-hot + quant + loss ------
// Block = 256 thr = 4 waves; 64 rows per block; grid = 1024.
// NEW: codebook tiles split ACROSS waves (wave w -> ct = 8w..8w+7), each wave
// computes all 4 row-tiles (M=64). Same total MFMA, 4x fewer B-frag loads
// (512 MB -> 128 MB L2 traffic), 24 MFMA per 4 loads for latency hiding.
// Cross-wave argmin combine via LDS.
__global__ __launch_bounds__(256) void k_main(const float* __restrict__ in,
                                              const float* __restrict__ cb,
                                              const bf16x8* __restrict__ cbh,
                                              const bf16x8* __restrict__ cbl,
                                              const float* __restrict__ ne,
                                              float* __restrict__ out,
                                              float2* __restrict__ enc2,
                                              int* __restrict__ hist,
                                              double* __restrict__ loss) {
    __shared__ float X[64][65];      // 16.6 KB; all access patterns <=2-way alias (free)
    __shared__ float ne_s[512];
    __shared__ int   sidx[64];
    __shared__ float smin[4][64];    // per-wave argmin candidates
    __shared__ int   smid[4][64];
    int tid = threadIdx.x;
    int n0 = blockIdx.x * 64;
    int b  = n0 >> 12, t0 = n0 & (T_ - 1);

    { // stage x-tile: 4096 floats, 16 per thread, coalesced
        int tl = tid & 63, dg = tid >> 6;
#pragma unroll
        for (int i = 0; i < 16; ++i) {
            int d = dg * 16 + i;
            X[d][tl] = in[((size_t)b * 64 + d) * T_ + t0 + tl];
        }
    }
    ne_s[tid] = ne[tid];
    ne_s[tid + 256] = ne[tid + 256];
    __syncthreads();

    int w = tid >> 6, lane = tid & 63;
    int col = lane & 15, q = lane >> 4;

    // A-frags for ALL 4 row-tiles: A[mt][m][k=ks*32+q*8+j] = X[d][mt*16+col]
    bf16x8 Ah[4][2], Al[4][2];
#pragma unroll
    for (int mt = 0; mt < 4; ++mt)
#pragma unroll
        for (int ks = 0; ks < 2; ++ks) {
            bf16x8 h, l;
#pragma unroll
            for (int j = 0; j < 8; ++j) {
                float v = X[ks * 32 + q * 8 + j][mt * 16 + col];
                __bf16 hv = (__bf16)v;
                __bf16 lv = (__bf16)(v - (float)hv);
                h[j] = hv; l[j] = lv;
            }
            Ah[mt][ks] = h; Al[mt][ks] = l;
        }

    float m1[4][4]; int i1[4][4];
#pragma unroll
    for (int mt = 0; mt < 4; ++mt)
#pragma unroll
        for (int e = 0; e < 4; ++e) { m1[mt][e] = 3.4e38f; i1[mt][e] = 0; }

#pragma unroll 2
    for (int c8 = 0; c8 < 8; ++c8) {
        int ct = w * 8 + c8;                 // this wave's codebook tile
        bf16x8 Bh0 = cbh[(ct * 2 + 0) * 64 + lane];
        bf16x8 Bh1 = cbh[(ct * 2 + 1) * 64 + lane];
        bf16x8 Bl0 = cbl[(ct * 2 + 0) * 64 + lane];
        bf16x8 Bl1 = cbl[(ct * 2 + 1) * 64 + lane];
        float nev = ne_s[ct * 16 + col];
        int code = ct * 16 + col;
#pragma unroll
        for (int mt = 0; mt < 4; ++mt) {
            f32x4 acc = {0.f, 0.f, 0.f, 0.f};
            acc = __builtin_amdgcn_mfma_f32_16x16x32_bf16(Ah[mt][0], Bh0, acc, 0, 0, 0);
            acc = __builtin_amdgcn_mfma_f32_16x16x32_bf16(Ah[mt][1], Bh1, acc, 0, 0, 0);
            acc = __builtin_amdgcn_mfma_f32_16x16x32_bf16(Ah[mt][0], Bl0, acc, 0, 0, 0);
            acc = __builtin_amdgcn_mfma_f32_16x16x32_bf16(Al[mt][0], Bh0, acc, 0, 0, 0);
            acc = __builtin_amdgcn_mfma_f32_16x16x32_bf16(Ah[mt][1], Bl1, acc, 0, 0, 0);
            acc = __builtin_amdgcn_mfma_f32_16x16x32_bf16(Al[mt][1], Bh1, acc, 0, 0, 0);
            // lo*lo terms ~2^-32 relative: negligible, dropped
#pragma unroll
            for (int e = 0; e < 4; ++e) {
                float sc = fmaf(-2.f, acc[e], nev);   // ||e||^2 - 2 x.e
                bool lt = sc < m1[mt][e];             // strict: ties keep lowest ct
                i1[mt][e] = lt ? code : i1[mt][e];
                m1[mt][e] = lt ? sc : m1[mt][e];
            }
        }
    }

    // per-wave argmin across the 16 lanes (same q) holding this row's columns
#pragma unroll
    for (int mt = 0; mt < 4; ++mt)
#pragma unroll
        for (int e = 0; e < 4; ++e) {
            float a1 = m1[mt][e]; int ai = i1[mt][e];
#pragma unroll
            for (int off = 1; off < 16; off <<= 1) {
                float o1 = __shfl_xor(a1, off);
                int   oi = __shfl_xor(ai, off);
                bool tk = (o1 < a1) || (o1 == a1 && oi < ai);  // tie -> lower index
                a1 = tk ? o1 : a1; ai = tk ? oi : ai;
            }
            if (col == 0) { smin[w][mt * 16 + q * 4 + e] = a1; smid[w][mt * 16 + q * 4 + e] = ai; }
        }
    __syncthreads();

    // combine the 4 waves' candidates (wave order = ascending code blocks)
    if (tid < 64) {
        float a1 = smin[0][tid]; int ai = smid[0][tid];
#pragma unroll
        for (int w2 = 1; w2 < 4; ++w2) {
            float o1 = smin[w2][tid]; int oi = smid[w2][tid];
            bool tk = (o1 < a1) || (o1 == a1 && oi < ai);
            a1 = tk ? o1 : a1; ai = tk ? oi : ai;
        }
        sidx[tid] = ai;
    }
    __syncthreads();

    // --- one-hot rows: 256 float2 cols per row, 64 rows (base 8B-aligned) ---
#pragma unroll 4
    for (int i = 0; i < 64; ++i) {
        int id = sidx[i];                      // uniform LDS read -> broadcast
        float2 v;
        v.x = ((id >> 1) == tid && (id & 1) == 0) ? 1.f : 0.f;
        v.y = ((id >> 1) == tid && (id & 1) == 1) ? 1.f : 0.f;
        enc2[(size_t)(n0 + i) * 256 + tid] = v;
    }

    // --- quantized + loss: lane = row, 16 dims per thread ---
    int tl = tid & 63, dg = tid >> 6;
    int idq = sidx[tl];
    const float4* cq4 = (const float4*)(cb + (size_t)idq * 64 + dg * 16);
    float* qp = out + 1 + (size_t)b * D_ * T_ + (size_t)(dg * 16) * T_ + t0 + tl;

    float lsum = 0.f;
#pragma unroll
    for (int j4 = 0; j4 < 4; ++j4) {
        float4 qv = cq4[j4];
        float qe[4] = {qv.x, qv.y, qv.z, qv.w};
#pragma unroll
        for (int e = 0; e < 4; ++e) {
            int dl = j4 * 4 + e;               // 0..15
            float xv = X[dg * 16 + dl][tl];
            float diff = qe[e] - xv;
            lsum = fmaf(diff, diff, lsum);
            qp[(size_t)dl * T_] = xv + diff;   // straight-through: x + (q - x)
        }
    }
    if (tid < 64) atomicAdd(&hist[idq], 1);    // one count per row (device scope, proven cheap R0)

#pragma unroll
    for (int off = 32; off > 0; off >>= 1) lsum += __shfl_down(lsum, off);
    __shared__ float wsum[4];
    if ((tid & 63) == 0) wsum[tid >> 6] = lsum;
    __syncthreads();
    if (tid == 0) {
        double s = (double)wsum[0] + (double)wsum[1] + (double)wsum[2] + (double)wsum[3];
        atomicAdd(loss, s);
    }
}

// ---------------- K6: finalize loss + perplexity (trivial, as in R0) --------
__global__ __launch_bounds__(512) void k6_final(const int* __restrict__ hist,
                                                const double* __restrict__ loss,
                                                float* __restrict__ out) {
    __shared__ double sh[512];
    int k = threadIdx.x;
    double p = (double)hist[k] / (double)N_;
    sh[k] = p * log(p + 1e-10);
    __syncthreads();
    for (int s = 256; s > 0; s >>= 1) {
        if (k < s) sh[k] += sh[k + s];
        __syncthreads();
    }
    if (k == 0) {
        out[1 + Q_] = (float)exp(-sh[0]);
        out[0] = (float)(1.25 * (*loss) / (double)Q_);
    }
}

extern "C" void kernel_launch(void* const* d_in, const int* in_sizes, int n_in,
                              void* d_out, int out_size, void* d_ws, size_t ws_size,
                              hipStream_t stream) {
    const float* in = (const float*)d_in[0];   // [16, 64, 4096] fp32
    const float* cb = (const float*)d_in[1];   // [512, 64] fp32
    float* out = (float*)d_out;
    char* ws = (char*)d_ws;

    double* loss  = (double*)(ws + WS_LOSS);
    int* hist     = (int*)(ws + WS_HIST);
    float* ne     = (float*)(ws + WS_NE);
    bf16x8* cbh   = (bf16x8*)(ws + WS_CBH);
    bf16x8* cbl   = (bf16x8*)(ws + WS_CBL);

    float2* enc2 = (float2*)(out + ENC_OFF);

    k0_init<<<16, 256, 0, stream>>>(cb, ne, hist, loss, cbh, cbl);
    k_main<<<N_ / 64, 256, 0, stream>>>(in, cb, cbh, cbl, ne, out, enc2, hist, loss);
    k6_final<<<1, 512, 0, stream>>>(hist, loss, out);
}